// Round 8
// baseline (499.299 us; speedup 1.0000x reference)
//
#include <hip/hip_runtime.h>
#include <math.h>

namespace {

constexpr int BB   = 2;
constexpr int CC   = 48;
constexpr int NHEAD= 8;
constexpr int CPH  = 6;     // channels per head
constexpr int HID  = 127;   // int(48*2.66)
constexpr int QKVC = 144;
constexpr int PINC = 254;
constexpr int N1   = 256*256;
constexpr int N2   = 128*128;
constexpr size_t PS2 = (size_t)BB*CC*N2;   // one nlwt plane
constexpr size_t NB1 = (size_t)BB*CC*N1;

using short8  = __attribute__((ext_vector_type(8))) short;
using floatx4 = __attribute__((ext_vector_type(4))) float;

__device__ __forceinline__ float b2f(unsigned short u) {
    unsigned int x = ((unsigned int)u) << 16;
    float f; __builtin_memcpy(&f, &x, 4); return f;
}
__device__ __forceinline__ unsigned short f2b(float f) {
    unsigned int x; __builtin_memcpy(&x, &f, 4);
    unsigned int r = (x + 0x7FFFu + ((x >> 16) & 1u)) >> 16;   // RNE
    return (unsigned short)r;
}
__device__ __forceinline__ unsigned int pack2(float lo, float hi) {
    return (unsigned int)f2b(lo) | ((unsigned int)f2b(hi) << 16);
}

// tanh-form GELU via hw exp (|err vs erf-GELU| < ~1e-3, within bf16 tolerance)
__device__ __forceinline__ float gelu_t(float x) {
    float z = 1.5957691216057308f * (x + 0.044715f * x * x * x);
    float e = __expf(z);
    return x * (1.0f - 1.0f / (e + 1.0f));
}

__global__ void k_zero(float* __restrict__ p, int n)
{
    int i = blockIdx.x*256 + threadIdx.x;
    if (i < n) p[i] = 0.f;
}

// generic repack w[oc][K] -> wt[c][oc] (fp32, used by pout)
__global__ void k_repw(const float* __restrict__ w, float* __restrict__ wt, int O, int K)
{
    int i = blockIdx.x*256 + threadIdx.x;
    if (i < O*K) {
        int c = i / O, oc = i - c*O;
        wt[c*O + oc] = w[oc*K + c];
    }
}

// pack conv weights [oc][48] fp32 -> per-lane MFMA A-fragments bf16
template<int OCR, int OCT>
__global__ void k_packw_mfma(const float* __restrict__ w, unsigned short* __restrict__ wf)
{
    int i = blockIdx.x*256 + threadIdx.x;
    if (i >= OCT*2*64) return;
    int lane = i & 63, ts = i >> 6;
    int s = ts & 1, t = ts >> 1;
    int oc = t*16 + (lane & 15);
    int kb = s*32 + (lane >> 4)*8;
    float v[8];
#pragma unroll
    for (int j = 0; j < 8; ++j) {
        int k = kb + j;
        v[j] = (oc < OCR && k < 48) ? w[oc*48 + k] : 0.f;
    }
    uint4 o;
    o.x = pack2(v[0], v[1]); o.y = pack2(v[2], v[3]);
    o.z = pack2(v[4], v[5]); o.w = pack2(v[6], v[7]);
    *(uint4*)(wf + (size_t)i*8) = o;
}

// ---------------- LN (channel): fp32 in -> bf16 LN'd out, PIXEL-MAJOR [px][48] ----------------
__global__ __launch_bounds__(256) void k_ln_t(const float* __restrict__ X,
                       const float* __restrict__ lw, const float* __restrict__ lb,
                       unsigned short* __restrict__ xh, int Ns)
{
    int g = blockIdx.x*256 + threadIdx.x;      // over BB*Ns/2
    int half = Ns >> 1;
    int b = g >= half ? 1 : 0;
    int pp = (g - b*half)*2;
    const float* xb = X + (size_t)b*CC*Ns + pp;
    float v0[CC], v1[CC];
    float s0=0.f, s20=0.f, s1=0.f, s21=0.f;
#pragma unroll
    for (int c = 0; c < CC; ++c) {
        float2 v = *(const float2*)(xb + (size_t)c*Ns);
        v0[c]=v.x; v1[c]=v.y;
        s0 += v.x; s20 = fmaf(v.x,v.x,s20);
        s1 += v.y; s21 = fmaf(v.y,v.y,s21);
    }
    float mu0 = s0*(1.0f/CC), mu1 = s1*(1.0f/CC);
    float i0 = 1.0f/sqrtf(s20*(1.0f/CC)-mu0*mu0+1e-5f);
    float i1 = 1.0f/sqrtf(s21*(1.0f/CC)-mu1*mu1+1e-5f);
    unsigned short* r0 = xh + ((size_t)b*Ns + pp)*48;
    unsigned short* r1 = r0 + 48;
#pragma unroll
    for (int j = 0; j < 6; ++j) {
        uint4 o0, o1;
        float y[8], z[8];
#pragma unroll
        for (int e = 0; e < 8; ++e) {
            int c = j*8 + e;
            float w = lw[c], bb2 = lb[c];
            y[e] = (v0[c]-mu0)*i0*w + bb2;
            z[e] = (v1[c]-mu1)*i1*w + bb2;
        }
        o0.x = pack2(y[0],y[1]); o0.y = pack2(y[2],y[3]);
        o0.z = pack2(y[4],y[5]); o0.w = pack2(y[6],y[7]);
        o1.x = pack2(z[0],z[1]); o1.y = pack2(z[2],z[3]);
        o1.z = pack2(z[4],z[5]); o1.w = pack2(z[6],z[7]);
        *(uint4*)(r0 + j*8) = o0;
        *(uint4*)(r1 + j*8) = o1;
    }
}

// ---------------- 1x1 conv via MFMA: xh [px][48] bf16 -> out [oc][px] bf16 ----------------
template<int OCR, int OCT>
__global__ __launch_bounds__(256) void k_conv_mfma(const unsigned short* __restrict__ xh,
                       const unsigned short* __restrict__ wf,
                       unsigned short* __restrict__ out, int Ns)
{
    int wid = (blockIdx.x*256 + (int)threadIdx.x) >> 6;
    int lane = threadIdx.x & 63;
    int tpb = Ns >> 4;                 // 16-px tiles per image
    int b = wid / tpb, pxt = wid - b*tpb;
    int px0 = pxt << 4;
    int col = lane & 15, grp = lane >> 4;
    const unsigned short* xb = xh + ((size_t)b*Ns + px0 + col)*48 + grp*8;
    short8 b0 = *(const short8*)(xb);        // k = grp*8 + j
    short8 b1 = *(const short8*)(xb + 32);   // k = 32 + grp*8 + j (k>=48 garbage * zero weight)
    unsigned short* ob = out + (size_t)b*OCR*Ns + px0 + col;
    int ocb0 = grp*4;
#pragma unroll
    for (int t = 0; t < OCT; ++t) {
        floatx4 acc = {};
        short8 a0 = *(const short8*)(wf + (size_t)((t*2+0)*64 + lane)*8);
        short8 a1 = *(const short8*)(wf + (size_t)((t*2+1)*64 + lane)*8);
        acc = __builtin_amdgcn_mfma_f32_16x16x32_bf16(a0, b0, acc, 0, 0, 0);
        acc = __builtin_amdgcn_mfma_f32_16x16x32_bf16(a1, b1, acc, 0, 0, 0);
#pragma unroll
        for (int r = 0; r < 4; ++r) {
            int oc = t*16 + ocb0 + r;
            if (OCR % 16 == 0 || oc < OCR)
                ob[(size_t)oc*Ns] = f2b(acc[r]);
        }
    }
}

// ---------------- depthwise 3x3, 2x8 tile per thread, sliding 4-row window ----------------
__device__ __forceinline__ void load_row10(const unsigned short* __restrict__ p,
                                           bool lok, bool rrok, float (&f)[10])
{
    uint4 cv = *(const uint4*)p;            // 8 bf16, 16B aligned
    unsigned int u0=cv.x,u1=cv.y,u2=cv.z,u3=cv.w;
    f[1]=b2f((unsigned short)(u0&0xffffu)); f[2]=b2f((unsigned short)(u0>>16));
    f[3]=b2f((unsigned short)(u1&0xffffu)); f[4]=b2f((unsigned short)(u1>>16));
    f[5]=b2f((unsigned short)(u2&0xffffu)); f[6]=b2f((unsigned short)(u2>>16));
    f[7]=b2f((unsigned short)(u3&0xffffu)); f[8]=b2f((unsigned short)(u3>>16));
    f[0] = lok  ? b2f(p[-1]) : 0.f;
    f[9] = rrok ? b2f(p[8])  : 0.f;
}

__device__ __forceinline__ void dw2x8(const unsigned short* __restrict__ plane,
                                      const float* __restrict__ w9,
                                      int y0, int x0, int Hs, int Ws, float (&acc)[2][8])
{
#pragma unroll
    for (int r = 0; r < 2; ++r)
#pragma unroll
        for (int i = 0; i < 8; ++i) acc[r][i] = 0.f;
    bool lok = x0 > 0, rrok = x0 + 8 < Ws;
#pragma unroll
    for (int ir = 0; ir < 4; ++ir) {
        int r = y0 + ir - 1;
        if (r < 0 || r >= Hs) continue;     // zero-pad row
        float f[10];
        load_row10(plane + (size_t)r*Ws + x0, lok, rrok, f);
#pragma unroll
        for (int ky = 0; ky < 3; ++ky) {
            int orow = ir - ky;
            if (orow < 0 || orow > 1) continue;
            float w0 = w9[ky*3], w1 = w9[ky*3+1], w2 = w9[ky*3+2];
#pragma unroll
            for (int i = 0; i < 8; ++i)
                acc[orow][i] = fmaf(f[i], w0, fmaf(f[i+1], w1, fmaf(f[i+2], w2, acc[orow][i])));
        }
    }
}

// qkv path: bf16 in -> bf16 out, 2x8 tile
__global__ __launch_bounds__(256) void k_dw3v(const unsigned short* __restrict__ in,
                      const float* __restrict__ w,
                      unsigned short* __restrict__ out, int Hs, int Ws, int lgNgt, int lgWq)
{
    int g = blockIdx.x*256 + threadIdx.x;    // over BB*QKVC*(Hs/2)*(Ws/8)
    int t = g & ((1<<lgNgt)-1), bc = g >> lgNgt;
    int c = bc % QKVC;
    int y0 = (t >> lgWq) << 1, x0 = (t & ((1<<lgWq)-1)) << 3;
    int Ns = Hs*Ws;
    float acc[2][8];
    dw2x8(in + (size_t)bc*Ns, w + c*9, y0, x0, Hs, Ws, acc);
    unsigned short* ob = out + (size_t)bc*Ns + (size_t)y0*Ws + x0;
#pragma unroll
    for (int r = 0; r < 2; ++r) {
        uint4 o;
        o.x = pack2(acc[r][0],acc[r][1]); o.y = pack2(acc[r][2],acc[r][3]);
        o.z = pack2(acc[r][4],acc[r][5]); o.w = pack2(acc[r][6],acc[r][7]);
        *(uint4*)(ob + (size_t)r*Ws) = o;
    }
}

// ffn path: two planes + gelu gate -> bf16, 2x8 tile
__global__ __launch_bounds__(256) void k_dwgate(const unsigned short* __restrict__ pin,
                         const float* __restrict__ dww,
                         unsigned short* __restrict__ gate, int Hs, int Ws, int lgNgt, int lgWq)
{
    int g = blockIdx.x*256 + threadIdx.x;    // over BB*HID*(Hs/2)*(Ws/8)
    int t = g & ((1<<lgNgt)-1), bc = g >> lgNgt;
    int b = bc / HID, c = bc - b*HID;
    int y0 = (t >> lgWq) << 1, x0 = (t & ((1<<lgWq)-1)) << 3;
    int Ns = Hs*Ws;
    float a1[2][8], a2[2][8];
    dw2x8(pin + ((size_t)b*PINC + c)*Ns,       dww + c*9,       y0, x0, Hs, Ws, a1);
    dw2x8(pin + ((size_t)b*PINC + HID + c)*Ns, dww + (c+HID)*9, y0, x0, Hs, Ws, a2);
    unsigned short* ob = gate + (size_t)bc*Ns + (size_t)y0*Ws + x0;
#pragma unroll
    for (int r = 0; r < 2; ++r) {
        uint4 o;
        o.x = pack2(gelu_t(a1[r][0])*a2[r][0], gelu_t(a1[r][1])*a2[r][1]);
        o.y = pack2(gelu_t(a1[r][2])*a2[r][2], gelu_t(a1[r][3])*a2[r][3]);
        o.z = pack2(gelu_t(a1[r][4])*a2[r][4], gelu_t(a1[r][5])*a2[r][5]);
        o.w = pack2(gelu_t(a1[r][6])*a2[r][6], gelu_t(a1[r][7])*a2[r][7]);
        *(uint4*)(ob + (size_t)r*Ws) = o;
    }
}

// ---------------- q/k norms + gram reduction (bf16 in, 2 px/lane) ----------------
__global__ __launch_bounds__(256) void k_qk_stats(const unsigned short* __restrict__ qkvd,
                                                  float* __restrict__ st, int Ns)
{
    const int NBLK = 32;
    int bh = blockIdx.x / NBLK, blk = blockIdx.x % NBLK;
    int b = bh / NHEAD, h = bh % NHEAD;
    const unsigned short* qb = qkvd + ((size_t)b*QKVC + h*CPH)*Ns;
    const unsigned short* kb = qkvd + ((size_t)b*QKVC + 48 + h*CPH)*Ns;
    float vals[48];
#pragma unroll
    for (int i = 0; i < 48; ++i) vals[i] = 0.f;
    for (int n = blk*512 + (int)threadIdx.x*2; n < Ns; n += NBLK*512) {
        float q0[CPH], q1[CPH], k0[CPH], k1[CPH];
#pragma unroll
        for (int i = 0; i < CPH; ++i) {
            unsigned int qu = *(const unsigned int*)(qb + (size_t)i*Ns + n);
            unsigned int ku = *(const unsigned int*)(kb + (size_t)i*Ns + n);
            q0[i] = b2f((unsigned short)(qu & 0xffffu)); q1[i] = b2f((unsigned short)(qu >> 16));
            k0[i] = b2f((unsigned short)(ku & 0xffffu)); k1[i] = b2f((unsigned short)(ku >> 16));
        }
#pragma unroll
        for (int i = 0; i < CPH; ++i) {
            vals[i]   = fmaf(q0[i],q0[i], fmaf(q1[i],q1[i], vals[i]));
            vals[6+i] = fmaf(k0[i],k0[i], fmaf(k1[i],k1[i], vals[6+i]));
        }
#pragma unroll
        for (int i = 0; i < CPH; ++i)
#pragma unroll
            for (int j = 0; j < CPH; ++j)
                vals[12+i*6+j] = fmaf(q0[i],k0[j], fmaf(q1[i],k1[j], vals[12+i*6+j]));
    }
    __shared__ float red[4][48];
    int lane = threadIdx.x & 63, wave = threadIdx.x >> 6;
#pragma unroll
    for (int i = 0; i < 48; ++i) {
        float v = vals[i];
#pragma unroll
        for (int off = 32; off > 0; off >>= 1) v += __shfl_down(v, off);
        if (lane == 0) red[wave][i] = v;
    }
    __syncthreads();
    if ((int)threadIdx.x < 48) {
        int i = threadIdx.x;
        float v = red[0][i] + red[1][i] + red[2][i] + red[3][i];
        float* dst;
        if (i < 6)       dst = st + b*48 + h*CPH + i;
        else if (i < 12) dst = st + 96 + b*48 + h*CPH + (i-6);
        else             dst = st + 192 + (b*NHEAD+h)*36 + (i-12);
        atomicAdd(dst, v);
    }
}

// ---------------- softmax 6x6 + fold into proj: Mt[b][c][oc] = (proj @ blockdiag(attn))^T ----------------
__global__ void k_attn(const float* __restrict__ st, const float* __restrict__ temp,
                       const float* __restrict__ projw, float* __restrict__ Mt)
{
    int t = threadIdx.x;
    if (t >= BB*NHEAD) return;
    int b = t / NHEAD, h = t % NHEAD;
    const float* sqq = st + b*48 + h*CPH;
    const float* sqk = st + 96 + b*48 + h*CPH;
    const float* g   = st + 192 + (b*NHEAD+h)*36;
    float T = temp[h];
    float nq[CPH], nk[CPH];
#pragma unroll
    for (int i = 0; i < CPH; ++i) {
        nq[i] = fmaxf(sqrtf(sqq[i]), 1e-12f);
        nk[i] = fmaxf(sqrtf(sqk[i]), 1e-12f);
    }
    float a[CPH][CPH];
#pragma unroll
    for (int c = 0; c < CPH; ++c) {
        float l[CPH]; float m = -1e30f;
#pragma unroll
        for (int d = 0; d < CPH; ++d) {
            l[d] = g[c*6+d] / (nq[c]*nk[d]) * T;
            m = fmaxf(m, l[d]);
        }
        float ssum = 0.f;
#pragma unroll
        for (int d = 0; d < CPH; ++d) { l[d] = expf(l[d]-m); ssum += l[d]; }
        float r = 1.0f/ssum;
#pragma unroll
        for (int d = 0; d < CPH; ++d) a[c][d] = l[d]*r;
    }
    // M[oc][h*6+d] = sum_c proj[oc][h*6+c] * a[c][d]; store transposed Mt[b][h*6+d][oc]
    float* mb = Mt + b*CC*CC;
#pragma unroll
    for (int d = 0; d < CPH; ++d) {
        for (int oc = 0; oc < CC; ++oc) {
            float m = 0.f;
#pragma unroll
            for (int c = 0; c < CPH; ++c)
                m = fmaf(projw[oc*CC + h*CPH + c], a[c][d], m);
            mb[(h*CPH+d)*CC + oc] = m;
        }
    }
}

// ---------------- fused (proj·attn)·v + residual: K=48 GEMM, 1 px/thread, all 48 oc ----------------
__global__ __launch_bounds__(256) void k_av_proj(const unsigned short* __restrict__ qkvd,
                          const float* __restrict__ Mt, const float* __restrict__ X,
                          float* __restrict__ x1, int Ns)
{
    int g = blockIdx.x*256 + threadIdx.x;      // over BB*Ns
    int b = g >= Ns ? 1 : 0;
    int px = g - b*Ns;
    const unsigned short* vb = qkvd + ((size_t)b*QKVC + 96)*Ns + px;
    const float* mt = Mt + b*CC*CC;
    float a[CC];
#pragma unroll
    for (int i = 0; i < CC; ++i) a[i] = 0.f;
#pragma unroll
    for (int c0 = 0; c0 < CC; c0 += 8) {
        unsigned short gv[8];
#pragma unroll
        for (int u = 0; u < 8; ++u)
            gv[u] = vb[(size_t)(c0+u)*Ns];
#pragma unroll
        for (int u = 0; u < 8; ++u) {
            float tv = b2f(gv[u]);
            const float* wr = mt + (c0+u)*CC;
#pragma unroll
            for (int i = 0; i < CC; ++i)
                a[i] = fmaf(tv, wr[i], a[i]);
        }
    }
    const float* xb = X + (size_t)b*CC*Ns + px;
    float* ob = x1 + (size_t)b*CC*Ns + px;
#pragma unroll
    for (int i = 0; i < CC; ++i)
        ob[(size_t)i*Ns] = xb[(size_t)i*Ns] + a[i];
}

// ---------------- ffn part 2: 1x1 conv 127->48 + residual, 1 px/thread, all 48 oc ----------------
template<int U>
__device__ __forceinline__ void pout1_chunk(const unsigned short* __restrict__ gb, int c0, int Ns,
                                            const float* __restrict__ wt, float (&a)[CC])
{
    unsigned short gv[U];
#pragma unroll
    for (int u = 0; u < U; ++u)
        gv[u] = gb[(size_t)(c0+u)*Ns];
#pragma unroll
    for (int u = 0; u < U; ++u) {
        float tv = b2f(gv[u]);
        const float* wr = wt + (c0+u)*CC;
#pragma unroll
        for (int i = 0; i < CC; ++i)
            a[i] = fmaf(tv, wr[i], a[i]);
    }
}

__global__ __launch_bounds__(256) void k_pout(const unsigned short* __restrict__ gate,
                       const float* __restrict__ wt, const float* __restrict__ x1,
                       float* __restrict__ out, int Ns)
{
    int g = blockIdx.x*256 + threadIdx.x;      // over BB*Ns
    int b = g >= Ns ? 1 : 0;
    int px = g - b*Ns;
    const unsigned short* gb = gate + (size_t)b*HID*Ns + px;
    float a[CC];
#pragma unroll
    for (int i = 0; i < CC; ++i) a[i] = 0.f;
    int c = 0;
    for (; c + 8 <= HID; c += 8)
        pout1_chunk<8>(gb, c, Ns, wt, a);
    pout1_chunk<7>(gb, c, Ns, wt, a);          // 120..126
    const float* xb = x1 + (size_t)b*CC*Ns + px;
    float* ob = out + (size_t)b*CC*Ns + px;
#pragma unroll
    for (int i = 0; i < CC; ++i)
        ob[(size_t)i*Ns] = xb[(size_t)i*Ns] + a[i];
}

// ---------------- nlwt ----------------
__global__ __launch_bounds__(256) void k_nlwt(const float* __restrict__ X, float* __restrict__ A4)
{
    int g = blockIdx.x*256 + threadIdx.x;   // over BB*CC*N2
    int n = g & (N2-1); int bc = g >> 14;
    int h1 = n >> 7, w1 = n & 127;
    int hb = (h1+1)&127, wb = (w1+1)&127;
    const float* xp = X + (size_t)bc * N1;
    float t1, t2, t3, t4;
    {
        int y=h1, z=w1;
        float c0=xp[(2*y)*256+2*z], c1=xp[(2*y)*256+2*z+1], c2=xp[(2*y+1)*256+2*z], c3=xp[(2*y+1)*256+2*z+1];
        t1 = 0.5f*(-c0 - c1 - c2 + c3);
    }
    {
        int y=hb, z=w1;
        float c0=xp[(2*y)*256+2*z], c1=xp[(2*y)*256+2*z+1], c2=xp[(2*y+1)*256+2*z], c3=xp[(2*y+1)*256+2*z+1];
        t2 = 0.5f*( c0 - c1 + c2 + c3);
    }
    {
        int y=h1, z=wb;
        float c0=xp[(2*y)*256+2*z], c1=xp[(2*y)*256+2*z+1], c2=xp[(2*y+1)*256+2*z], c3=xp[(2*y+1)*256+2*z+1];
        t3 = 0.5f*( c0 + c1 - c2 + c3);
    }
    {
        int y=hb, z=wb;
        float c0=xp[(2*y)*256+2*z], c1=xp[(2*y)*256+2*z+1], c2=xp[(2*y+1)*256+2*z], c3=xp[(2*y+1)*256+2*z+1];
        t4 = 0.5f*( c0 - c1 - c2 - c3);
    }
    size_t o = (size_t)bc*N2 + n;
    A4[o]           = -t1 + t2 + t3 - t4;
    A4[PS2 + o]     = -t1 - t2 - t3 - t4;
    A4[2*PS2 + o]   = -t1 - t2 + t3 + t4;
    A4[3*PS2 + o]   =  t1 - t2 + t3 - t4;
}

// ---------------- inlwt ----------------
__global__ __launch_bounds__(256) void k_inlwt(const float* __restrict__ Ain, const float* __restrict__ A4,
                        float* __restrict__ out)
{
    int g = blockIdx.x*256 + threadIdx.x;   // over BB*CC*N2
    int n = g & (N2-1); int bc = g >> 14;
    int h1 = n >> 7, w1 = n & 127;
    int hm = (h1-1)&127, wm = (w1-1)&127;
    const float* I0 = Ain + (size_t)bc*N2;
    const float* I1 = A4 + PS2   + (size_t)bc*N2;
    const float* I2 = A4 + 2*PS2 + (size_t)bc*N2;
    const float* I3 = A4 + 3*PS2 + (size_t)bc*N2;
    int i00 = h1*128+w1, i10 = hm*128+w1, i01 = h1*128+wm, i11 = hm*128+wm;
    float t1, t2, t3, t4;
    { float a=I0[i00], b2=I1[i00], c2=I2[i00], d2=I3[i00]; t1 = -a - b2 - c2 + d2; }
    { float a=I0[i10], b2=I1[i10], c2=I2[i10], d2=I3[i10]; t2 =  a - b2 - c2 - d2; }
    { float a=I0[i01], b2=I1[i01], c2=I2[i01], d2=I3[i01]; t3 =  a - b2 + c2 + d2; }
    { float a=I0[i11], b2=I1[i11], c2=I2[i11], d2=I3[i11]; t4 = -a - b2 + c2 - d2; }
    float y00 = 0.125f*(-t1 + t2 + t3 + t4);
    float y01 = 0.125f*(-t1 - t2 + t3 - t4);
    float y10 = 0.125f*(-t1 + t2 - t3 - t4);
    float y11 = 0.125f*( t1 + t2 + t3 - t4);
    float* ob = out + (size_t)bc * N1;
    int oy = h1*2, ox = w1*2;
    ob[(size_t)oy*256 + ox]       = y00;
    ob[(size_t)oy*256 + ox + 1]   = y01;
    ob[(size_t)(oy+1)*256 + ox]   = y10;
    ob[(size_t)(oy+1)*256 + ox+1] = y11;
}

// ---------------- gfm: channel stats, two-stage ----------------
constexpr int CSEG = 8;
__global__ __launch_bounds__(256) void k_chstat_part(const float* __restrict__ b1, const float* __restrict__ b2,
                         float* __restrict__ ps, float* __restrict__ pm)
{
    int bc = blockIdx.x;            // 0..BB*96-1
    int seg = blockIdx.y;           // 0..CSEG-1
    int b = bc / 96, ch = bc % 96;
    const float* src = (ch < 48 ? b1 + ((size_t)b*CC + ch)*N1
                                : b2 + ((size_t)b*CC + (ch-48))*N1) + (size_t)seg*(N1/CSEG);
    const float4* s4 = (const float4*)src;
    float s = 0.f, m = -1e30f;
    for (int i = threadIdx.x; i < N1/CSEG/4; i += 256) {
        float4 v = s4[i];
        s += v.x+v.y+v.z+v.w;
        m = fmaxf(m, fmaxf(fmaxf(v.x,v.y), fmaxf(v.z,v.w)));
    }
    int lane = threadIdx.x & 63, wave = threadIdx.x >> 6;
    __shared__ float rs[4], rm[4];
#pragma unroll
    for (int off = 32; off > 0; off >>= 1) {
        s += __shfl_down(s, off);
        m = fmaxf(m, __shfl_down(m, off));
    }
    if (lane == 0) { rs[wave] = s; rm[wave] = m; }
    __syncthreads();
    if (threadIdx.x == 0) {
        ps[bc*CSEG + seg] = rs[0]+rs[1]+rs[2]+rs[3];
        pm[bc*CSEG + seg] = fmaxf(fmaxf(rm[0],rm[1]), fmaxf(rm[2],rm[3]));
    }
}

__global__ void k_chstat_fin(const float* __restrict__ ps, const float* __restrict__ pm,
                             float* __restrict__ avg, float* __restrict__ mxo)
{
    int t = threadIdx.x;
    if (t >= BB*96) return;
    float s = 0.f, m = -1e30f;
#pragma unroll
    for (int j = 0; j < CSEG; ++j) {
        s += ps[t*CSEG+j];
        m = fmaxf(m, pm[t*CSEG+j]);
    }
    avg[t] = s*(1.0f/N1);
    mxo[t] = m;
}

// ---------------- gfm: channel attention MLP ----------------
__global__ void k_cw(const float* __restrict__ avg, const float* __restrict__ mx,
                     const float* __restrict__ w1, const float* __restrict__ w2,
                     float* __restrict__ cw)
{
    int t = threadIdx.x;
    if (t >= BB*96) return;
    int b = t / 96, o = t % 96;
    float ta[6], tm[6];
#pragma unroll
    for (int j = 0; j < 6; ++j) {
        float sa = 0.f, sm = 0.f;
        for (int i = 0; i < 96; ++i) {
            float w = w1[j*96+i];
            sa = fmaf(w, avg[b*96+i], sa);
            sm = fmaf(w, mx[b*96+i], sm);
        }
        ta[j] = sa > 0.f ? sa : 0.f;
        tm[j] = sm > 0.f ? sm : 0.f;
    }
    float ua = 0.f, um = 0.f;
#pragma unroll
    for (int j = 0; j < 6; ++j) {
        ua = fmaf(w2[o*6+j], ta[j], ua);
        um = fmaf(w2[o*6+j], tm[j], um);
    }
    float z = ua + um;
    cw[t] = 1.0f/(1.0f+expf(-z));
}

// ---------------- gfm: weighted combine + spatial stats ----------------
__global__ __launch_bounds__(256) void k_gfm_out(const float* __restrict__ b1, const float* __restrict__ b2,
                          const float* __restrict__ cw, float* __restrict__ ob,
                          float* __restrict__ savg, float* __restrict__ smax)
{
    int g = blockIdx.x*256 + threadIdx.x;   // BB*N1
    int b = g >> 16, p = g & (N1-1);
    float s = 0.f, m = -1e30f;
#pragma unroll
    for (int c = 0; c < CC; ++c) {
        size_t idx = ((size_t)b*CC + c)*N1 + p;
        float o = cw[b*96 + c]*b1[idx] + cw[b*96 + 48 + c]*b2[idx];
        ob[idx] = o;
        s += o; m = fmaxf(m, o);
    }
    savg[(size_t)b*N1 + p] = s*(1.0f/CC);
    smax[(size_t)b*N1 + p] = m;
}

// ---------------- gfm: 7x7 spatial attention + final multiply ----------------
__global__ __launch_bounds__(256) void k_final(const float* __restrict__ savg, const float* __restrict__ smax,
                        const float* __restrict__ saw, const float* __restrict__ sab,
                        const float* __restrict__ ob, float* __restrict__ out)
{
    int g = blockIdx.x*256 + threadIdx.x;
    int b = g >> 16, p = g & (N1-1);
    int y = p >> 8, x = p & 255;
    float s = sab[0];
    const float* av = savg + (size_t)b*N1;
    const float* mx = smax + (size_t)b*N1;
#pragma unroll
    for (int ky = 0; ky < 7; ++ky) {
        int yy = y + ky - 3;
        bool yok = (yy >= 0) && (yy < 256);
        int yc = yy < 0 ? 0 : (yy > 255 ? 255 : yy);
#pragma unroll
        for (int kx = 0; kx < 7; ++kx) {
            int xx = x + kx - 3;
            bool ok = yok && (xx >= 0) && (xx < 256);
            int xc = xx < 0 ? 0 : (xx > 255 ? 255 : xx);
            int idx = yc*256 + xc;
            float a = av[idx], m2 = mx[idx];
            s = fmaf(ok ? a  : 0.f, saw[ky*7+kx], s);
            s = fmaf(ok ? m2 : 0.f, saw[49 + ky*7+kx], s);
        }
    }
    float sig = 1.0f/(1.0f+expf(-s));
#pragma unroll
    for (int c = 0; c < CC; ++c) {
        size_t idx = ((size_t)b*CC + c)*N1 + p;
        out[idx] = sig * ob[idx];
    }
}

} // anonymous namespace

extern "C" void kernel_launch(void* const* d_in, const int* in_sizes, int n_in,
                              void* d_out, int out_size, void* d_ws, size_t ws_size,
                              hipStream_t stream)
{
    const float* x    = (const float*)d_in[0];
    const float* ln1w = (const float*)d_in[1];
    const float* ln1b = (const float*)d_in[2];
    const float* temp = (const float*)d_in[3];
    const float* qkvw = (const float*)d_in[4];
    const float* qkvdw= (const float*)d_in[5];
    const float* projw= (const float*)d_in[6];
    const float* ln2w = (const float*)d_in[7];
    const float* ln2b = (const float*)d_in[8];
    const float* pinw = (const float*)d_in[9];
    const float* ffdw = (const float*)d_in[10];
    const float* poutw= (const float*)d_in[11];
    const float* caw1 = (const float*)d_in[12];
    const float* caw2 = (const float*)d_in[13];
    const float* saw  = (const float*)d_in[14];
    const float* sab  = (const float*)d_in[15];

    float* wsf  = (float*)d_ws;
    float* A4   = wsf;                               // 4 planes of (B,C,128,128)
    float* br1  = A4 + 4*PS2;
    float* br2  = br1 + NB1;
    float* x1b  = br2 + NB1;                         // tblock x1 / gfm out buffer
    float* tbA  = x1b + NB1;
    float* qkv  = tbA + PS2;                         // bf16 qkv conv out / bf16 pin_out
    float* qkvd = qkv + (size_t)BB*QKVC*N1;          // bf16 xhat; bf16 dwconv out; bf16 gate
    float* stats= qkvd + (size_t)BB*QKVC*N1;
    float* wfqf = stats + 4096;                      // mfma-packed qkv w
    float* wfpf = wfqf + 4608;                       // mfma-packed pin w
    float* wor  = wfpf + 8192;                       // repacked pout w [127][48] fp32
    float* chps = wor + HID*48;                      // chstat partial sums
    float* chpm = chps + 192*CSEG;                   // chstat partial maxs
    float* savg = chpm + 192*CSEG;
    float* smax = savg + (size_t)BB*N1;
    float* Mt   = smax + (size_t)BB*N1;              // fused proj@attn matrices [B][48][48]

    unsigned short* wfq = (unsigned short*)wfqf;
    unsigned short* wfp = (unsigned short*)wfpf;

    k_packw_mfma<QKVC, 9><<<(9*2*64+255)/256, 256, 0, stream>>>(qkvw, wfq);
    k_packw_mfma<PINC, 16><<<(16*2*64+255)/256, 256, 0, stream>>>(pinw, wfp);
    k_repw<<<(HID*48+255)/256, 256, 0, stream>>>(poutw, wor, 48, HID);

    auto tb = [&](const float* Xin, float* outp, int Hs, int Ws) {
        int Ns = Hs*Ws;
        int npix = BB*Ns;
        int lgWq = 31 - __builtin_clz(Ws >> 3);
        int lgNgt = (31 - __builtin_clz(Hs >> 1)) + lgWq;
        unsigned short* xhat = (unsigned short*)qkvd;   // dead before dw3v/dwgate write qkvd
        k_zero<<<3, 256, 0, stream>>>(stats, 768);
        k_ln_t<<<npix/512, 256, 0, stream>>>(Xin, ln1w, ln1b, xhat, Ns);
        k_conv_mfma<QKVC, 9><<<npix/64, 256, 0, stream>>>(xhat, wfq, (unsigned short*)qkv, Ns);
        k_dw3v<<<(BB*QKVC*(Ns/16))/256, 256, 0, stream>>>((const unsigned short*)qkv, qkvdw,
                                                          (unsigned short*)qkvd, Hs, Ws, lgNgt, lgWq);
        k_qk_stats<<<BB*NHEAD*32, 256, 0, stream>>>((const unsigned short*)qkvd, stats, Ns);
        k_attn<<<1, 64, 0, stream>>>(stats, temp, projw, Mt);
        k_av_proj<<<npix/256, 256, 0, stream>>>((const unsigned short*)qkvd, Mt, Xin, x1b, Ns);
        k_ln_t<<<npix/512, 256, 0, stream>>>(x1b, ln2w, ln2b, xhat, Ns);
        k_conv_mfma<PINC, 16><<<npix/64, 256, 0, stream>>>(xhat, wfp, (unsigned short*)qkv, Ns);
        k_dwgate<<<(BB*HID*(Ns/16)+255)/256, 256, 0, stream>>>((const unsigned short*)qkv, ffdw,
                                                        (unsigned short*)qkvd, Hs, Ws, lgNgt, lgWq);
        k_pout<<<npix/256, 256, 0, stream>>>((const unsigned short*)qkvd, wor, x1b, outp, Ns);
    };

    tb(x, br1, 256, 256);
    k_nlwt<<<(BB*CC*N2)/256, 256, 0, stream>>>(x, A4);
    tb(A4, tbA, 128, 128);
    k_inlwt<<<(BB*CC*N2)/256, 256, 0, stream>>>(tbA, A4, br2);
    dim3 gc(BB*96, CSEG);
    k_chstat_part<<<gc, 256, 0, stream>>>(br1, br2, chps, chpm);
    k_chstat_fin<<<1, 256, 0, stream>>>(chps, chpm, stats + 1344, stats + 1536);
    k_cw<<<1, 256, 0, stream>>>(stats + 1344, stats + 1536, caw1, caw2, stats + 1728);
    k_gfm_out<<<(BB*N1)/256, 256, 0, stream>>>(br1, br2, stats + 1728, x1b, savg, smax);
    k_final<<<(BB*N1)/256, 256, 0, stream>>>(savg, smax, saw, sab, x1b, (float*)d_out);
}

// Round 9
// 427.276 us; speedup vs baseline: 1.1686x; 1.1686x over previous
//
#include <hip/hip_runtime.h>
#include <math.h>

namespace {

constexpr int BB   = 2;
constexpr int CC   = 48;
constexpr int NHEAD= 8;
constexpr int CPH  = 6;     // channels per head
constexpr int HID  = 127;   // int(48*2.66)
constexpr int QKVC = 144;
constexpr int PINC = 254;
constexpr int N1   = 256*256;
constexpr int N2   = 128*128;
constexpr size_t PS2 = (size_t)BB*CC*N2;   // one nlwt plane
constexpr size_t NB1 = (size_t)BB*CC*N1;

using short8  = __attribute__((ext_vector_type(8))) short;
using floatx4 = __attribute__((ext_vector_type(4))) float;

__device__ __forceinline__ float b2f(unsigned short u) {
    unsigned int x = ((unsigned int)u) << 16;
    float f; __builtin_memcpy(&f, &x, 4); return f;
}
__device__ __forceinline__ unsigned short f2b(float f) {
    unsigned int x; __builtin_memcpy(&x, &f, 4);
    unsigned int r = (x + 0x7FFFu + ((x >> 16) & 1u)) >> 16;   // RNE
    return (unsigned short)r;
}
__device__ __forceinline__ unsigned int pack2(float lo, float hi) {
    return (unsigned int)f2b(lo) | ((unsigned int)f2b(hi) << 16);
}

// tanh-form GELU via hw exp (|err vs erf-GELU| < ~1e-3, within bf16 tolerance)
__device__ __forceinline__ float gelu_t(float x) {
    float z = 1.5957691216057308f * (x + 0.044715f * x * x * x);
    float e = __expf(z);
    return x * (1.0f - 1.0f / (e + 1.0f));
}

__global__ void k_zero(float* __restrict__ p, int n)
{
    int i = blockIdx.x*256 + threadIdx.x;
    if (i < n) p[i] = 0.f;
}

// generic repack w[oc][K] -> wt[c][oc] (fp32, used by pout)
__global__ void k_repw(const float* __restrict__ w, float* __restrict__ wt, int O, int K)
{
    int i = blockIdx.x*256 + threadIdx.x;
    if (i < O*K) {
        int c = i / O, oc = i - c*O;
        wt[c*O + oc] = w[oc*K + c];
    }
}

// pack conv weights [oc][48] fp32 -> per-lane MFMA A-fragments bf16
template<int OCR, int OCT>
__global__ void k_packw_mfma(const float* __restrict__ w, unsigned short* __restrict__ wf)
{
    int i = blockIdx.x*256 + threadIdx.x;
    if (i >= OCT*2*64) return;
    int lane = i & 63, ts = i >> 6;
    int s = ts & 1, t = ts >> 1;
    int oc = t*16 + (lane & 15);
    int kb = s*32 + (lane >> 4)*8;
    float v[8];
#pragma unroll
    for (int j = 0; j < 8; ++j) {
        int k = kb + j;
        v[j] = (oc < OCR && k < 48) ? w[oc*48 + k] : 0.f;
    }
    uint4 o;
    o.x = pack2(v[0], v[1]); o.y = pack2(v[2], v[3]);
    o.z = pack2(v[4], v[5]); o.w = pack2(v[6], v[7]);
    *(uint4*)(wf + (size_t)i*8) = o;
}

// ---------------- LN (channel): fp32 in -> bf16 LN'd out, PIXEL-MAJOR [px][48] ----------------
__global__ __launch_bounds__(256) void k_ln_t(const float* __restrict__ X,
                       const float* __restrict__ lw, const float* __restrict__ lb,
                       unsigned short* __restrict__ xh, int Ns)
{
    int g = blockIdx.x*256 + threadIdx.x;      // over BB*Ns/2
    int half = Ns >> 1;
    int b = g >= half ? 1 : 0;
    int pp = (g - b*half)*2;
    const float* xb = X + (size_t)b*CC*Ns + pp;
    float v0[CC], v1[CC];
    float s0=0.f, s20=0.f, s1=0.f, s21=0.f;
#pragma unroll
    for (int c = 0; c < CC; ++c) {
        float2 v = *(const float2*)(xb + (size_t)c*Ns);
        v0[c]=v.x; v1[c]=v.y;
        s0 += v.x; s20 = fmaf(v.x,v.x,s20);
        s1 += v.y; s21 = fmaf(v.y,v.y,s21);
    }
    float mu0 = s0*(1.0f/CC), mu1 = s1*(1.0f/CC);
    float i0 = 1.0f/sqrtf(s20*(1.0f/CC)-mu0*mu0+1e-5f);
    float i1 = 1.0f/sqrtf(s21*(1.0f/CC)-mu1*mu1+1e-5f);
    unsigned short* r0 = xh + ((size_t)b*Ns + pp)*48;
    unsigned short* r1 = r0 + 48;
#pragma unroll
    for (int j = 0; j < 6; ++j) {
        uint4 o0, o1;
        float y[8], z[8];
#pragma unroll
        for (int e = 0; e < 8; ++e) {
            int c = j*8 + e;
            float w = lw[c], bb2 = lb[c];
            y[e] = (v0[c]-mu0)*i0*w + bb2;
            z[e] = (v1[c]-mu1)*i1*w + bb2;
        }
        o0.x = pack2(y[0],y[1]); o0.y = pack2(y[2],y[3]);
        o0.z = pack2(y[4],y[5]); o0.w = pack2(y[6],y[7]);
        o1.x = pack2(z[0],z[1]); o1.y = pack2(z[2],z[3]);
        o1.z = pack2(z[4],z[5]); o1.w = pack2(z[6],z[7]);
        *(uint4*)(r0 + j*8) = o0;
        *(uint4*)(r1 + j*8) = o1;
    }
}

// ---------------- 1x1 conv via MFMA: xh [px][48] bf16 -> out [oc][px] bf16 ----------------
template<int OCR, int OCT>
__global__ __launch_bounds__(256) void k_conv_mfma(const unsigned short* __restrict__ xh,
                       const unsigned short* __restrict__ wf,
                       unsigned short* __restrict__ out, int Ns)
{
    int wid = (blockIdx.x*256 + (int)threadIdx.x) >> 6;
    int lane = threadIdx.x & 63;
    int tpb = Ns >> 4;                 // 16-px tiles per image
    int b = wid / tpb, pxt = wid - b*tpb;
    int px0 = pxt << 4;
    int col = lane & 15, grp = lane >> 4;
    const unsigned short* xb = xh + ((size_t)b*Ns + px0 + col)*48 + grp*8;
    short8 b0 = *(const short8*)(xb);        // k = grp*8 + j
    short8 b1 = *(const short8*)(xb + 32);   // k = 32 + grp*8 + j (k>=48 garbage * zero weight)
    unsigned short* ob = out + (size_t)b*OCR*Ns + px0 + col;
    int ocb0 = grp*4;
#pragma unroll
    for (int t = 0; t < OCT; ++t) {
        floatx4 acc = {};
        short8 a0 = *(const short8*)(wf + (size_t)((t*2+0)*64 + lane)*8);
        short8 a1 = *(const short8*)(wf + (size_t)((t*2+1)*64 + lane)*8);
        acc = __builtin_amdgcn_mfma_f32_16x16x32_bf16(a0, b0, acc, 0, 0, 0);
        acc = __builtin_amdgcn_mfma_f32_16x16x32_bf16(a1, b1, acc, 0, 0, 0);
#pragma unroll
        for (int r = 0; r < 4; ++r) {
            int oc = t*16 + ocb0 + r;
            if (OCR % 16 == 0 || oc < OCR)
                ob[(size_t)oc*Ns] = f2b(acc[r]);
        }
    }
}

// ---------------- depthwise 3x3, 2x8 tile per thread, sliding 4-row window ----------------
__device__ __forceinline__ void load_row10(const unsigned short* __restrict__ p,
                                           bool lok, bool rrok, float (&f)[10])
{
    uint4 cv = *(const uint4*)p;            // 8 bf16, 16B aligned
    unsigned int u0=cv.x,u1=cv.y,u2=cv.z,u3=cv.w;
    f[1]=b2f((unsigned short)(u0&0xffffu)); f[2]=b2f((unsigned short)(u0>>16));
    f[3]=b2f((unsigned short)(u1&0xffffu)); f[4]=b2f((unsigned short)(u1>>16));
    f[5]=b2f((unsigned short)(u2&0xffffu)); f[6]=b2f((unsigned short)(u2>>16));
    f[7]=b2f((unsigned short)(u3&0xffffu)); f[8]=b2f((unsigned short)(u3>>16));
    f[0] = lok  ? b2f(p[-1]) : 0.f;
    f[9] = rrok ? b2f(p[8])  : 0.f;
}

__device__ __forceinline__ void dw2x8(const unsigned short* __restrict__ plane,
                                      const float* __restrict__ w9,
                                      int y0, int x0, int Hs, int Ws, float (&acc)[2][8])
{
#pragma unroll
    for (int r = 0; r < 2; ++r)
#pragma unroll
        for (int i = 0; i < 8; ++i) acc[r][i] = 0.f;
    bool lok = x0 > 0, rrok = x0 + 8 < Ws;
#pragma unroll
    for (int ir = 0; ir < 4; ++ir) {
        int r = y0 + ir - 1;
        if (r < 0 || r >= Hs) continue;     // zero-pad row
        float f[10];
        load_row10(plane + (size_t)r*Ws + x0, lok, rrok, f);
#pragma unroll
        for (int ky = 0; ky < 3; ++ky) {
            int orow = ir - ky;
            if (orow < 0 || orow > 1) continue;
            float w0 = w9[ky*3], w1 = w9[ky*3+1], w2 = w9[ky*3+2];
#pragma unroll
            for (int i = 0; i < 8; ++i)
                acc[orow][i] = fmaf(f[i], w0, fmaf(f[i+1], w1, fmaf(f[i+2], w2, acc[orow][i])));
        }
    }
}

// qkv path: bf16 in -> bf16 out, 2x8 tile
__global__ __launch_bounds__(256) void k_dw3v(const unsigned short* __restrict__ in,
                      const float* __restrict__ w,
                      unsigned short* __restrict__ out, int Hs, int Ws, int lgNgt, int lgWq)
{
    int g = blockIdx.x*256 + threadIdx.x;    // over BB*QKVC*(Hs/2)*(Ws/8)
    int t = g & ((1<<lgNgt)-1), bc = g >> lgNgt;
    int c = bc % QKVC;
    int y0 = (t >> lgWq) << 1, x0 = (t & ((1<<lgWq)-1)) << 3;
    int Ns = Hs*Ws;
    float acc[2][8];
    dw2x8(in + (size_t)bc*Ns, w + c*9, y0, x0, Hs, Ws, acc);
    unsigned short* ob = out + (size_t)bc*Ns + (size_t)y0*Ws + x0;
#pragma unroll
    for (int r = 0; r < 2; ++r) {
        uint4 o;
        o.x = pack2(acc[r][0],acc[r][1]); o.y = pack2(acc[r][2],acc[r][3]);
        o.z = pack2(acc[r][4],acc[r][5]); o.w = pack2(acc[r][6],acc[r][7]);
        *(uint4*)(ob + (size_t)r*Ws) = o;
    }
}

// ffn path: two planes + gelu gate -> bf16, 2x8 tile
__global__ __launch_bounds__(256) void k_dwgate(const unsigned short* __restrict__ pin,
                         const float* __restrict__ dww,
                         unsigned short* __restrict__ gate, int Hs, int Ws, int lgNgt, int lgWq)
{
    int g = blockIdx.x*256 + threadIdx.x;    // over BB*HID*(Hs/2)*(Ws/8)
    int t = g & ((1<<lgNgt)-1), bc = g >> lgNgt;
    int b = bc / HID, c = bc - b*HID;
    int y0 = (t >> lgWq) << 1, x0 = (t & ((1<<lgWq)-1)) << 3;
    int Ns = Hs*Ws;
    float a1[2][8], a2[2][8];
    dw2x8(pin + ((size_t)b*PINC + c)*Ns,       dww + c*9,       y0, x0, Hs, Ws, a1);
    dw2x8(pin + ((size_t)b*PINC + HID + c)*Ns, dww + (c+HID)*9, y0, x0, Hs, Ws, a2);
    unsigned short* ob = gate + (size_t)bc*Ns + (size_t)y0*Ws + x0;
#pragma unroll
    for (int r = 0; r < 2; ++r) {
        uint4 o;
        o.x = pack2(gelu_t(a1[r][0])*a2[r][0], gelu_t(a1[r][1])*a2[r][1]);
        o.y = pack2(gelu_t(a1[r][2])*a2[r][2], gelu_t(a1[r][3])*a2[r][3]);
        o.z = pack2(gelu_t(a1[r][4])*a2[r][4], gelu_t(a1[r][5])*a2[r][5]);
        o.w = pack2(gelu_t(a1[r][6])*a2[r][6], gelu_t(a1[r][7])*a2[r][7]);
        *(uint4*)(ob + (size_t)r*Ws) = o;
    }
}

// ---------------- q/k norms + gram reduction (bf16 in, 2 px/lane) ----------------
__global__ __launch_bounds__(256) void k_qk_stats(const unsigned short* __restrict__ qkvd,
                                                  float* __restrict__ st, int Ns)
{
    const int NBLK = 32;
    int bh = blockIdx.x / NBLK, blk = blockIdx.x % NBLK;
    int b = bh / NHEAD, h = bh % NHEAD;
    const unsigned short* qb = qkvd + ((size_t)b*QKVC + h*CPH)*Ns;
    const unsigned short* kb = qkvd + ((size_t)b*QKVC + 48 + h*CPH)*Ns;
    float vals[48];
#pragma unroll
    for (int i = 0; i < 48; ++i) vals[i] = 0.f;
    for (int n = blk*512 + (int)threadIdx.x*2; n < Ns; n += NBLK*512) {
        float q0[CPH], q1[CPH], k0[CPH], k1[CPH];
#pragma unroll
        for (int i = 0; i < CPH; ++i) {
            unsigned int qu = *(const unsigned int*)(qb + (size_t)i*Ns + n);
            unsigned int ku = *(const unsigned int*)(kb + (size_t)i*Ns + n);
            q0[i] = b2f((unsigned short)(qu & 0xffffu)); q1[i] = b2f((unsigned short)(qu >> 16));
            k0[i] = b2f((unsigned short)(ku & 0xffffu)); k1[i] = b2f((unsigned short)(ku >> 16));
        }
#pragma unroll
        for (int i = 0; i < CPH; ++i) {
            vals[i]   = fmaf(q0[i],q0[i], fmaf(q1[i],q1[i], vals[i]));
            vals[6+i] = fmaf(k0[i],k0[i], fmaf(k1[i],k1[i], vals[6+i]));
        }
#pragma unroll
        for (int i = 0; i < CPH; ++i)
#pragma unroll
            for (int j = 0; j < CPH; ++j)
                vals[12+i*6+j] = fmaf(q0[i],k0[j], fmaf(q1[i],k1[j], vals[12+i*6+j]));
    }
    __shared__ float red[4][48];
    int lane = threadIdx.x & 63, wave = threadIdx.x >> 6;
#pragma unroll
    for (int i = 0; i < 48; ++i) {
        float v = vals[i];
#pragma unroll
        for (int off = 32; off > 0; off >>= 1) v += __shfl_down(v, off);
        if (lane == 0) red[wave][i] = v;
    }
    __syncthreads();
    if ((int)threadIdx.x < 48) {
        int i = threadIdx.x;
        float v = red[0][i] + red[1][i] + red[2][i] + red[3][i];
        float* dst;
        if (i < 6)       dst = st + b*48 + h*CPH + i;
        else if (i < 12) dst = st + 96 + b*48 + h*CPH + (i-6);
        else             dst = st + 192 + (b*NHEAD+h)*36 + (i-12);
        atomicAdd(dst, v);
    }
}

// ---------------- softmax 6x6 + fold into proj: Mt[b][c][oc] = (proj @ blockdiag(attn))^T ----------------
__global__ void k_attn(const float* __restrict__ st, const float* __restrict__ temp,
                       const float* __restrict__ projw, float* __restrict__ Mt)
{
    int t = threadIdx.x;
    if (t >= BB*NHEAD) return;
    int b = t / NHEAD, h = t % NHEAD;
    const float* sqq = st + b*48 + h*CPH;
    const float* sqk = st + 96 + b*48 + h*CPH;
    const float* g   = st + 192 + (b*NHEAD+h)*36;
    float T = temp[h];
    float nq[CPH], nk[CPH];
#pragma unroll
    for (int i = 0; i < CPH; ++i) {
        nq[i] = fmaxf(sqrtf(sqq[i]), 1e-12f);
        nk[i] = fmaxf(sqrtf(sqk[i]), 1e-12f);
    }
    float a[CPH][CPH];
#pragma unroll
    for (int c = 0; c < CPH; ++c) {
        float l[CPH]; float m = -1e30f;
#pragma unroll
        for (int d = 0; d < CPH; ++d) {
            l[d] = g[c*6+d] / (nq[c]*nk[d]) * T;
            m = fmaxf(m, l[d]);
        }
        float ssum = 0.f;
#pragma unroll
        for (int d = 0; d < CPH; ++d) { l[d] = expf(l[d]-m); ssum += l[d]; }
        float r = 1.0f/ssum;
#pragma unroll
        for (int d = 0; d < CPH; ++d) a[c][d] = l[d]*r;
    }
    // M[oc][h*6+d] = sum_c proj[oc][h*6+c] * a[c][d]; store transposed Mt[b][h*6+d][oc]
    float* mb = Mt + b*CC*CC;
#pragma unroll
    for (int d = 0; d < CPH; ++d) {
        for (int oc = 0; oc < CC; ++oc) {
            float m = 0.f;
#pragma unroll
            for (int c = 0; c < CPH; ++c)
                m = fmaf(projw[oc*CC + h*CPH + c], a[c][d], m);
            mb[(h*CPH+d)*CC + oc] = m;
        }
    }
}

// ---------------- fused (proj·attn)·v + residual: K=48 GEMM, v bf16, 2 px/thread, 16-oc chunks ----------------
__global__ __launch_bounds__(256) void k_av_proj(const unsigned short* __restrict__ qkvd,
                          const float* __restrict__ Mt, const float* __restrict__ X,
                          float* __restrict__ x1, int Ns)
{
    int g = blockIdx.x*256 + threadIdx.x;      // over BB*Ns/2
    int half = Ns >> 1;
    int b = g >= half ? 1 : 0;
    int pp = (g - b*half)*2;
    int ocb = blockIdx.y * 16;
    const unsigned short* vb = qkvd + ((size_t)b*QKVC + 96)*Ns + pp;
    const float* mt = Mt + b*CC*CC;
    float a0[16], a1[16];
#pragma unroll
    for (int i = 0; i < 16; ++i) { a0[i] = 0.f; a1[i] = 0.f; }
#pragma unroll
    for (int c0 = 0; c0 < CC; c0 += 8) {
        unsigned int gv[8];
#pragma unroll
        for (int u = 0; u < 8; ++u)
            gv[u] = *(const unsigned int*)(vb + (size_t)(c0+u)*Ns);
#pragma unroll
        for (int u = 0; u < 8; ++u) {
            float t0 = b2f((unsigned short)(gv[u] & 0xffffu));
            float t1 = b2f((unsigned short)(gv[u] >> 16));
            const float* wr = mt + (c0+u)*CC + ocb;
#pragma unroll
            for (int i = 0; i < 16; ++i) {
                float w = wr[i];
                a0[i] = fmaf(t0, w, a0[i]);
                a1[i] = fmaf(t1, w, a1[i]);
            }
        }
    }
    const float* xb = X + (size_t)b*CC*Ns + pp;
    float* ob = x1 + (size_t)b*CC*Ns + pp;
#pragma unroll
    for (int i = 0; i < 16; ++i) {
        float2 xv = *(const float2*)(xb + (size_t)(ocb+i)*Ns);
        float2 o; o.x = xv.x + a0[i]; o.y = xv.y + a1[i];
        *(float2*)(ob + (size_t)(ocb+i)*Ns) = o;
    }
}

// ---------------- ffn part 2: 1x1 conv 127->48 + residual, 2 px/thread, 16-oc chunks ----------------
template<int U>
__device__ __forceinline__ void pout_chunk(const unsigned short* __restrict__ gb, int c0, int Ns,
                                           const float* __restrict__ wt, int ocb,
                                           float (&a0)[16], float (&a1)[16])
{
    unsigned int gv[U];
#pragma unroll
    for (int u = 0; u < U; ++u)
        gv[u] = *(const unsigned int*)(gb + (size_t)(c0+u)*Ns);
#pragma unroll
    for (int u = 0; u < U; ++u) {
        float t0 = b2f((unsigned short)(gv[u] & 0xffffu));
        float t1 = b2f((unsigned short)(gv[u] >> 16));
        const float* wr = wt + (c0+u)*48 + ocb;
#pragma unroll
        for (int i = 0; i < 16; ++i) {
            float w = wr[i];
            a0[i] = fmaf(t0, w, a0[i]);
            a1[i] = fmaf(t1, w, a1[i]);
        }
    }
}

__global__ __launch_bounds__(256) void k_pout(const unsigned short* __restrict__ gate,
                       const float* __restrict__ wt, const float* __restrict__ x1,
                       float* __restrict__ out, int Ns)
{
    int g = blockIdx.x*256 + threadIdx.x;      // over BB*Ns/2
    int half = Ns >> 1;
    int b = g >= half ? 1 : 0;
    int pp = (g - b*half)*2;
    int ocb = blockIdx.y * 16;
    const unsigned short* gb = gate + (size_t)b*HID*Ns + pp;
    float a0[16], a1[16];
#pragma unroll
    for (int i = 0; i < 16; ++i) { a0[i] = 0.f; a1[i] = 0.f; }
    int c = 0;
    for (; c + 8 <= HID; c += 8)
        pout_chunk<8>(gb, c, Ns, wt, ocb, a0, a1);
    pout_chunk<7>(gb, c, Ns, wt, ocb, a0, a1);   // 120..126
    const float* xb = x1 + (size_t)b*CC*Ns + pp;
    float* ob = out + (size_t)b*CC*Ns + pp;
#pragma unroll
    for (int i = 0; i < 16; ++i) {
        float2 xv = *(const float2*)(xb + (size_t)(ocb+i)*Ns);
        float2 o; o.x = xv.x + a0[i]; o.y = xv.y + a1[i];
        *(float2*)(ob + (size_t)(ocb+i)*Ns) = o;
    }
}

// ---------------- nlwt ----------------
__global__ __launch_bounds__(256) void k_nlwt(const float* __restrict__ X, float* __restrict__ A4)
{
    int g = blockIdx.x*256 + threadIdx.x;   // over BB*CC*N2
    int n = g & (N2-1); int bc = g >> 14;
    int h1 = n >> 7, w1 = n & 127;
    int hb = (h1+1)&127, wb = (w1+1)&127;
    const float* xp = X + (size_t)bc * N1;
    float t1, t2, t3, t4;
    {
        int y=h1, z=w1;
        float c0=xp[(2*y)*256+2*z], c1=xp[(2*y)*256+2*z+1], c2=xp[(2*y+1)*256+2*z], c3=xp[(2*y+1)*256+2*z+1];
        t1 = 0.5f*(-c0 - c1 - c2 + c3);
    }
    {
        int y=hb, z=w1;
        float c0=xp[(2*y)*256+2*z], c1=xp[(2*y)*256+2*z+1], c2=xp[(2*y+1)*256+2*z], c3=xp[(2*y+1)*256+2*z+1];
        t2 = 0.5f*( c0 - c1 + c2 + c3);
    }
    {
        int y=h1, z=wb;
        float c0=xp[(2*y)*256+2*z], c1=xp[(2*y)*256+2*z+1], c2=xp[(2*y+1)*256+2*z], c3=xp[(2*y+1)*256+2*z+1];
        t3 = 0.5f*( c0 + c1 - c2 + c3);
    }
    {
        int y=hb, z=wb;
        float c0=xp[(2*y)*256+2*z], c1=xp[(2*y)*256+2*z+1], c2=xp[(2*y+1)*256+2*z], c3=xp[(2*y+1)*256+2*z+1];
        t4 = 0.5f*( c0 - c1 - c2 - c3);
    }
    size_t o = (size_t)bc*N2 + n;
    A4[o]           = -t1 + t2 + t3 - t4;
    A4[PS2 + o]     = -t1 - t2 - t3 - t4;
    A4[2*PS2 + o]   = -t1 - t2 + t3 + t4;
    A4[3*PS2 + o]   =  t1 - t2 + t3 - t4;
}

// ---------------- inlwt ----------------
__global__ __launch_bounds__(256) void k_inlwt(const float* __restrict__ Ain, const float* __restrict__ A4,
                        float* __restrict__ out)
{
    int g = blockIdx.x*256 + threadIdx.x;   // over BB*CC*N2
    int n = g & (N2-1); int bc = g >> 14;
    int h1 = n >> 7, w1 = n & 127;
    int hm = (h1-1)&127, wm = (w1-1)&127;
    const float* I0 = Ain + (size_t)bc*N2;
    const float* I1 = A4 + PS2   + (size_t)bc*N2;
    const float* I2 = A4 + 2*PS2 + (size_t)bc*N2;
    const float* I3 = A4 + 3*PS2 + (size_t)bc*N2;
    int i00 = h1*128+w1, i10 = hm*128+w1, i01 = h1*128+wm, i11 = hm*128+wm;
    float t1, t2, t3, t4;
    { float a=I0[i00], b2=I1[i00], c2=I2[i00], d2=I3[i00]; t1 = -a - b2 - c2 + d2; }
    { float a=I0[i10], b2=I1[i10], c2=I2[i10], d2=I3[i10]; t2 =  a - b2 - c2 - d2; }
    { float a=I0[i01], b2=I1[i01], c2=I2[i01], d2=I3[i01]; t3 =  a - b2 + c2 + d2; }
    { float a=I0[i11], b2=I1[i11], c2=I2[i11], d2=I3[i11]; t4 = -a - b2 + c2 - d2; }
    float y00 = 0.125f*(-t1 + t2 + t3 + t4);
    float y01 = 0.125f*(-t1 - t2 + t3 - t4);
    float y10 = 0.125f*(-t1 + t2 - t3 - t4);
    float y11 = 0.125f*( t1 + t2 + t3 - t4);
    float* ob = out + (size_t)bc * N1;
    int oy = h1*2, ox = w1*2;
    ob[(size_t)oy*256 + ox]       = y00;
    ob[(size_t)oy*256 + ox + 1]   = y01;
    ob[(size_t)(oy+1)*256 + ox]   = y10;
    ob[(size_t)(oy+1)*256 + ox+1] = y11;
}

// ---------------- gfm: channel stats, two-stage ----------------
constexpr int CSEG = 8;
__global__ __launch_bounds__(256) void k_chstat_part(const float* __restrict__ b1, const float* __restrict__ b2,
                         float* __restrict__ ps, float* __restrict__ pm)
{
    int bc = blockIdx.x;            // 0..BB*96-1
    int seg = blockIdx.y;           // 0..CSEG-1
    int b = bc / 96, ch = bc % 96;
    const float* src = (ch < 48 ? b1 + ((size_t)b*CC + ch)*N1
                                : b2 + ((size_t)b*CC + (ch-48))*N1) + (size_t)seg*(N1/CSEG);
    const float4* s4 = (const float4*)src;
    float s = 0.f, m = -1e30f;
    for (int i = threadIdx.x; i < N1/CSEG/4; i += 256) {
        float4 v = s4[i];
        s += v.x+v.y+v.z+v.w;
        m = fmaxf(m, fmaxf(fmaxf(v.x,v.y), fmaxf(v.z,v.w)));
    }
    int lane = threadIdx.x & 63, wave = threadIdx.x >> 6;
    __shared__ float rs[4], rm[4];
#pragma unroll
    for (int off = 32; off > 0; off >>= 1) {
        s += __shfl_down(s, off);
        m = fmaxf(m, __shfl_down(m, off));
    }
    if (lane == 0) { rs[wave] = s; rm[wave] = m; }
    __syncthreads();
    if (threadIdx.x == 0) {
        ps[bc*CSEG + seg] = rs[0]+rs[1]+rs[2]+rs[3];
        pm[bc*CSEG + seg] = fmaxf(fmaxf(rm[0],rm[1]), fmaxf(rm[2],rm[3]));
    }
}

__global__ void k_chstat_fin(const float* __restrict__ ps, const float* __restrict__ pm,
                             float* __restrict__ avg, float* __restrict__ mxo)
{
    int t = threadIdx.x;
    if (t >= BB*96) return;
    float s = 0.f, m = -1e30f;
#pragma unroll
    for (int j = 0; j < CSEG; ++j) {
        s += ps[t*CSEG+j];
        m = fmaxf(m, pm[t*CSEG+j]);
    }
    avg[t] = s*(1.0f/N1);
    mxo[t] = m;
}

// ---------------- gfm: channel attention MLP ----------------
__global__ void k_cw(const float* __restrict__ avg, const float* __restrict__ mx,
                     const float* __restrict__ w1, const float* __restrict__ w2,
                     float* __restrict__ cw)
{
    int t = threadIdx.x;
    if (t >= BB*96) return;
    int b = t / 96, o = t % 96;
    float ta[6], tm[6];
#pragma unroll
    for (int j = 0; j < 6; ++j) {
        float sa = 0.f, sm = 0.f;
        for (int i = 0; i < 96; ++i) {
            float w = w1[j*96+i];
            sa = fmaf(w, avg[b*96+i], sa);
            sm = fmaf(w, mx[b*96+i], sm);
        }
        ta[j] = sa > 0.f ? sa : 0.f;
        tm[j] = sm > 0.f ? sm : 0.f;
    }
    float ua = 0.f, um = 0.f;
#pragma unroll
    for (int j = 0; j < 6; ++j) {
        ua = fmaf(w2[o*6+j], ta[j], ua);
        um = fmaf(w2[o*6+j], tm[j], um);
    }
    float z = ua + um;
    cw[t] = 1.0f/(1.0f+expf(-z));
}

// ---------------- gfm: weighted combine + spatial stats ----------------
__global__ __launch_bounds__(256) void k_gfm_out(const float* __restrict__ b1, const float* __restrict__ b2,
                          const float* __restrict__ cw, float* __restrict__ ob,
                          float* __restrict__ savg, float* __restrict__ smax)
{
    int g = blockIdx.x*256 + threadIdx.x;   // BB*N1
    int b = g >> 16, p = g & (N1-1);
    float s = 0.f, m = -1e30f;
#pragma unroll
    for (int c = 0; c < CC; ++c) {
        size_t idx = ((size_t)b*CC + c)*N1 + p;
        float o = cw[b*96 + c]*b1[idx] + cw[b*96 + 48 + c]*b2[idx];
        ob[idx] = o;
        s += o; m = fmaxf(m, o);
    }
    savg[(size_t)b*N1 + p] = s*(1.0f/CC);
    smax[(size_t)b*N1 + p] = m;
}

// ---------------- gfm: 7x7 spatial attention + final multiply ----------------
__global__ __launch_bounds__(256) void k_final(const float* __restrict__ savg, const float* __restrict__ smax,
                        const float* __restrict__ saw, const float* __restrict__ sab,
                        const float* __restrict__ ob, float* __restrict__ out)
{
    int g = blockIdx.x*256 + threadIdx.x;
    int b = g >> 16, p = g & (N1-1);
    int y = p >> 8, x = p & 255;
    float s = sab[0];
    const float* av = savg + (size_t)b*N1;
    const float* mx = smax + (size_t)b*N1;
#pragma unroll
    for (int ky = 0; ky < 7; ++ky) {
        int yy = y + ky - 3;
        bool yok = (yy >= 0) && (yy < 256);
        int yc = yy < 0 ? 0 : (yy > 255 ? 255 : yy);
#pragma unroll
        for (int kx = 0; kx < 7; ++kx) {
            int xx = x + kx - 3;
            bool ok = yok && (xx >= 0) && (xx < 256);
            int xc = xx < 0 ? 0 : (xx > 255 ? 255 : xx);
            int idx = yc*256 + xc;
            float a = av[idx], m2 = mx[idx];
            s = fmaf(ok ? a  : 0.f, saw[ky*7+kx], s);
            s = fmaf(ok ? m2 : 0.f, saw[49 + ky*7+kx], s);
        }
    }
    float sig = 1.0f/(1.0f+expf(-s));
#pragma unroll
    for (int c = 0; c < CC; ++c) {
        size_t idx = ((size_t)b*CC + c)*N1 + p;
        out[idx] = sig * ob[idx];
    }
}

} // anonymous namespace

extern "C" void kernel_launch(void* const* d_in, const int* in_sizes, int n_in,
                              void* d_out, int out_size, void* d_ws, size_t ws_size,
                              hipStream_t stream)
{
    const float* x    = (const float*)d_in[0];
    const float* ln1w = (const float*)d_in[1];
    const float* ln1b = (const float*)d_in[2];
    const float* temp = (const float*)d_in[3];
    const float* qkvw = (const float*)d_in[4];
    const float* qkvdw= (const float*)d_in[5];
    const float* projw= (const float*)d_in[6];
    const float* ln2w = (const float*)d_in[7];
    const float* ln2b = (const float*)d_in[8];
    const float* pinw = (const float*)d_in[9];
    const float* ffdw = (const float*)d_in[10];
    const float* poutw= (const float*)d_in[11];
    const float* caw1 = (const float*)d_in[12];
    const float* caw2 = (const float*)d_in[13];
    const float* saw  = (const float*)d_in[14];
    const float* sab  = (const float*)d_in[15];

    float* wsf  = (float*)d_ws;
    float* A4   = wsf;                               // 4 planes of (B,C,128,128)
    float* br1  = A4 + 4*PS2;
    float* br2  = br1 + NB1;
    float* x1b  = br2 + NB1;                         // tblock x1 / gfm out buffer
    float* tbA  = x1b + NB1;
    float* qkv  = tbA + PS2;                         // bf16 qkv conv out / bf16 pin_out
    float* qkvd = qkv + (size_t)BB*QKVC*N1;          // bf16 xhat; bf16 dwconv out; bf16 gate
    float* stats= qkvd + (size_t)BB*QKVC*N1;
    float* wfqf = stats + 4096;                      // mfma-packed qkv w
    float* wfpf = wfqf + 4608;                       // mfma-packed pin w
    float* wor  = wfpf + 8192;                       // repacked pout w [127][48] fp32
    float* chps = wor + HID*48;                      // chstat partial sums
    float* chpm = chps + 192*CSEG;                   // chstat partial maxs
    float* savg = chpm + 192*CSEG;
    float* smax = savg + (size_t)BB*N1;
    float* Mt   = smax + (size_t)BB*N1;              // fused proj@attn matrices [B][48][48]

    unsigned short* wfq = (unsigned short*)wfqf;
    unsigned short* wfp = (unsigned short*)wfpf;

    k_packw_mfma<QKVC, 9><<<(9*2*64+255)/256, 256, 0, stream>>>(qkvw, wfq);
    k_packw_mfma<PINC, 16><<<(16*2*64+255)/256, 256, 0, stream>>>(pinw, wfp);
    k_repw<<<(HID*48+255)/256, 256, 0, stream>>>(poutw, wor, 48, HID);

    auto tb = [&](const float* Xin, float* outp, int Hs, int Ws) {
        int Ns = Hs*Ws;
        int npix = BB*Ns;
        int lgWq = 31 - __builtin_clz(Ws >> 3);
        int lgNgt = (31 - __builtin_clz(Hs >> 1)) + lgWq;
        unsigned short* xhat = (unsigned short*)qkvd;   // dead before dw3v/dwgate write qkvd
        k_zero<<<3, 256, 0, stream>>>(stats, 768);
        k_ln_t<<<npix/512, 256, 0, stream>>>(Xin, ln1w, ln1b, xhat, Ns);
        k_conv_mfma<QKVC, 9><<<npix/64, 256, 0, stream>>>(xhat, wfq, (unsigned short*)qkv, Ns);
        k_dw3v<<<(BB*QKVC*(Ns/16))/256, 256, 0, stream>>>((const unsigned short*)qkv, qkvdw,
                                                          (unsigned short*)qkvd, Hs, Ws, lgNgt, lgWq);
        k_qk_stats<<<BB*NHEAD*32, 256, 0, stream>>>((const unsigned short*)qkvd, stats, Ns);
        k_attn<<<1, 64, 0, stream>>>(stats, temp, projw, Mt);
        dim3 g4(npix/512, 3);
        k_av_proj<<<g4, 256, 0, stream>>>((const unsigned short*)qkvd, Mt, Xin, x1b, Ns);
        k_ln_t<<<npix/512, 256, 0, stream>>>(x1b, ln2w, ln2b, xhat, Ns);
        k_conv_mfma<PINC, 16><<<npix/64, 256, 0, stream>>>(xhat, wfp, (unsigned short*)qkv, Ns);
        k_dwgate<<<(BB*HID*(Ns/16)+255)/256, 256, 0, stream>>>((const unsigned short*)qkv, ffdw,
                                                        (unsigned short*)qkvd, Hs, Ws, lgNgt, lgWq);
        dim3 g6(npix/512, 3);
        k_pout<<<g6, 256, 0, stream>>>((const unsigned short*)qkvd, wor, x1b, outp, Ns);
    };

    tb(x, br1, 256, 256);
    k_nlwt<<<(BB*CC*N2)/256, 256, 0, stream>>>(x, A4);
    tb(A4, tbA, 128, 128);
    k_inlwt<<<(BB*CC*N2)/256, 256, 0, stream>>>(tbA, A4, br2);
    dim3 gc(BB*96, CSEG);
    k_chstat_part<<<gc, 256, 0, stream>>>(br1, br2, chps, chpm);
    k_chstat_fin<<<1, 256, 0, stream>>>(chps, chpm, stats + 1344, stats + 1536);
    k_cw<<<1, 256, 0, stream>>>(stats + 1344, stats + 1536, caw1, caw2, stats + 1728);
    k_gfm_out<<<(BB*N1)/256, 256, 0, stream>>>(br1, br2, stats + 1728, x1b, savg, smax);
    k_final<<<(BB*N1)/256, 256, 0, stream>>>(savg, smax, saw, sab, x1b, (float*)d_out);
}